// Round 1
// baseline (413.445 us; speedup 1.0000x reference)
//
#include <hip/hip_runtime.h>
#include <hip/hip_bf16.h>

typedef __bf16 bf16_t;
typedef bf16_t bf16x8 __attribute__((ext_vector_type(8)));
typedef float f32x4 __attribute__((ext_vector_type(4)));

#define B_  128
#define T_  256
#define C_  64
#define H_  128
#define G_  512   // 4*H
#define BT  16    // batch rows per workgroup
#define HS  136   // h_lds row stride (bf16 elems): 272B -> 16B aligned rows, de-conflicted banks
#define HSZ (BT*HS)

__device__ __forceinline__ float sigmoid_fast(float z) {
    return __builtin_amdgcn_rcpf(1.0f + __builtin_amdgcn_exp2f(-1.4426950408889634f * z));
}
__device__ __forceinline__ float tanh_fast(float z) {
    return 1.0f - 2.0f * __builtin_amdgcn_rcpf(1.0f + __builtin_amdgcn_exp2f(2.8853900817779268f * z));
}

__global__ __launch_bounds__(256, 2) void lstm_fused(
    const float* __restrict__ x,     // [B,T,C]
    const float* __restrict__ w_ih,  // [C,4H]
    const float* __restrict__ w_hh,  // [C,4H,H]
    const float* __restrict__ b_ih,  // [C,4H]
    const float* __restrict__ b_hh,  // [C,4H]
    const float* __restrict__ w_fc,  // [C,H]
    const float* __restrict__ b_fc,  // [C]
    float* __restrict__ out)         // [B,C]
{
    const int c    = blockIdx.x & (C_ - 1);
    const int bt   = blockIdx.x >> 6;      // 0..7
    const int b0   = bt * BT;
    const int tid  = threadIdx.x;
    const int wid  = tid >> 6;             // wave 0..3
    const int lane = tid & 63;
    const int l16  = lane & 15;
    const int lg   = lane >> 4;            // 0..3

    __shared__ __align__(16) bf16_t h_lds[2 * HSZ];  // ping-pong h state (bf16)
    __shared__ float x_lds[BT * T_];                 // staged inputs for this (c, b-tile)

    // zero both h buffers
    for (int i = tid; i < 2 * HSZ; i += 256) h_lds[i] = (bf16_t)0.0f;
    // stage x[b0..b0+15, :, c] into LDS
    for (int i = tid; i < BT * T_; i += 256) {
        const int bl = i >> 8, t = i & 255;
        x_lds[i] = x[(size_t)(b0 + bl) * (T_ * C_) + (size_t)t * C_ + c];
    }

    // ---- preload per-wave weight fragments (bf16) + bias + w_ih into registers ----
    // wave `wid` owns gate-columns n = q*128 + wid*32 + u*16 + l16  (q=gate, u=subtile)
    bf16x8 bw[4][2][4];        // [gate][u][k-frag] : 128 VGPRs
    float  bias[4][2], wih[4][2];
    #pragma unroll
    for (int q = 0; q < 4; ++q) {
        #pragma unroll
        for (int u = 0; u < 2; ++u) {
            const int n = q * 128 + wid * 32 + u * 16 + l16;
            bias[q][u] = b_ih[c * G_ + n] + b_hh[c * G_ + n];
            wih[q][u]  = w_ih[c * G_ + n];
            #pragma unroll
            for (int kk = 0; kk < 4; ++kk) {
                const int k0 = kk * 32 + lg * 8;
                const float4 wa = *(const float4*)&w_hh[((size_t)(c * G_ + n)) * H_ + k0];
                const float4 wb = *(const float4*)&w_hh[((size_t)(c * G_ + n)) * H_ + k0 + 4];
                bf16x8 f;
                f[0] = (bf16_t)wa.x; f[1] = (bf16_t)wa.y; f[2] = (bf16_t)wa.z; f[3] = (bf16_t)wa.w;
                f[4] = (bf16_t)wb.x; f[5] = (bf16_t)wb.y; f[6] = (bf16_t)wb.z; f[7] = (bf16_t)wb.w;
                bw[q][u][kk] = f;
            }
        }
    }

    float cst[2][4];           // cell state: [u][r]  (col = wid*32+u*16+l16, row = lg*4+r)
    #pragma unroll
    for (int u = 0; u < 2; ++u)
        #pragma unroll
        for (int r = 0; r < 4; ++r) cst[u][r] = 0.0f;

    __syncthreads();

    const int a_base = l16 * HS;            // A-frag: row = l16, k = kk*32 + lg*8
    const int row_l  = lg * 4;              // C/D rows this lane owns: row_l..row_l+3
    const int col0   = wid * 32 + l16;      // C/D col (+ u*16)

    for (int t = 0; t < T_; ++t) {
        const int rd = (t & 1) * HSZ;
        const int wr = ((t + 1) & 1) * HSZ;

        // A fragments of h (same lane->k map as B fragments: layout-permutation safe)
        bf16x8 a[4];
        #pragma unroll
        for (int kk = 0; kk < 4; ++kk)
            a[kk] = *(const bf16x8*)&h_lds[rd + a_base + kk * 32 + lg * 8];

        // gates = h @ w_hh^T   (fp32 accum)
        f32x4 accv[4][2];
        #pragma unroll
        for (int q = 0; q < 4; ++q) {
            #pragma unroll
            for (int u = 0; u < 2; ++u) {
                f32x4 acc = {0.0f, 0.0f, 0.0f, 0.0f};
                #pragma unroll
                for (int kk = 0; kk < 4; ++kk)
                    acc = __builtin_amdgcn_mfma_f32_16x16x32_bf16(a[kk], bw[q][u][kk], acc, 0, 0, 0);
                accv[q][u] = acc;
            }
        }

        // activations + state update, fully in-lane
        float xv[4];
        #pragma unroll
        for (int r = 0; r < 4; ++r) xv[r] = x_lds[(row_l + r) * T_ + t];

        #pragma unroll
        for (int u = 0; u < 2; ++u) {
            #pragma unroll
            for (int r = 0; r < 4; ++r) {
                const float zi = accv[0][u][r] + xv[r] * wih[0][u] + bias[0][u];
                const float zf = accv[1][u][r] + xv[r] * wih[1][u] + bias[1][u];
                const float zg = accv[2][u][r] + xv[r] * wih[2][u] + bias[2][u];
                const float zo = accv[3][u][r] + xv[r] * wih[3][u] + bias[3][u];
                const float ig = sigmoid_fast(zi) * tanh_fast(zg);
                const float cn = sigmoid_fast(zf) * cst[u][r] + ig;
                cst[u][r] = cn;
                const float hn = sigmoid_fast(zo) * tanh_fast(cn);
                h_lds[wr + (row_l + r) * HS + col0 + u * 16] = (bf16_t)hn;
            }
        }
        __syncthreads();   // writes visible; safe: next step writes the buffer read this step
    }

    // ---- epilogue: out[b][c] = dot(h_T[b,:], w_fc[c,:]) + b_fc[c] ----
    // h_T is in buffer 0 (T_ even). 4 waves x 4 rows.
    #pragma unroll
    for (int rr = 0; rr < 4; ++rr) {
        const int row = wid * 4 + rr;
        const float h0 = (float)h_lds[row * HS + 2 * lane];
        const float h1 = (float)h_lds[row * HS + 2 * lane + 1];
        const float2 wf = *(const float2*)&w_fc[c * H_ + 2 * lane];
        float p = h0 * wf.x + h1 * wf.y;
        #pragma unroll
        for (int off = 32; off; off >>= 1) p += __shfl_xor(p, off);
        if (lane == 0) out[(size_t)(b0 + row) * C_ + c] = p + b_fc[c];
    }
}

extern "C" void kernel_launch(void* const* d_in, const int* in_sizes, int n_in,
                              void* d_out, int out_size, void* d_ws, size_t ws_size,
                              hipStream_t stream) {
    const float* x    = (const float*)d_in[0];
    const float* w_ih = (const float*)d_in[1];
    const float* w_hh = (const float*)d_in[2];
    const float* b_ih = (const float*)d_in[3];
    const float* b_hh = (const float*)d_in[4];
    const float* w_fc = (const float*)d_in[5];
    const float* b_fc = (const float*)d_in[6];
    float* out = (float*)d_out;

    dim3 grid(C_ * (B_ / BT));   // 512 workgroups
    dim3 block(256);
    lstm_fused<<<grid, block, 0, stream>>>(x, w_ih, w_hh, b_ih, b_hh, w_fc, b_fc, out);
}

// Round 2
// 397.744 us; speedup vs baseline: 1.0395x; 1.0395x over previous
//
#include <hip/hip_runtime.h>
#include <hip/hip_bf16.h>

typedef __bf16 bf16_t;
typedef bf16_t bf16x8 __attribute__((ext_vector_type(8)));
typedef bf16_t bf16x2 __attribute__((ext_vector_type(2)));
typedef float f32x4 __attribute__((ext_vector_type(4)));

#define B_  128
#define T_  256
#define C_  64
#define H_  128
#define G_  512   // 4*H
#define BT  16    // batch rows per workgroup
#define HS  136   // h_lds row stride (bf16): 272B rows, 16B-aligned
#define HSZ (BT*HS)
#define XS  257   // x_lds row stride (f32): 257%32==1 -> conflict-free column reads

__device__ __forceinline__ float sigmoid_fast(float z) {
    return __builtin_amdgcn_rcpf(1.0f + __builtin_amdgcn_exp2f(-1.4426950408889634f * z));
}
__device__ __forceinline__ float tanh_fast(float z) {
    return 1.0f - 2.0f * __builtin_amdgcn_rcpf(1.0f + __builtin_amdgcn_exp2f(2.8853900817779268f * z));
}
__device__ __forceinline__ uint32_t cvt_pk_bf16(float a, float b) {
    uint32_t r;
    asm("v_cvt_pk_bf16_f32 %0, %1, %2" : "=v"(r) : "v"(a), "v"(b));
    return r;
}

union AFrag { bf16x8 v; uint32_t w[4]; };

__global__ __launch_bounds__(256, 2) void lstm_fused(
    const float* __restrict__ x,     // [B,T,C]
    const float* __restrict__ w_ih,  // [C,4H]
    const float* __restrict__ w_hh,  // [C,4H,H]
    const float* __restrict__ b_ih,  // [C,4H]
    const float* __restrict__ b_hh,  // [C,4H]
    const float* __restrict__ w_fc,  // [C,H]
    const float* __restrict__ b_fc,  // [C]
    float* __restrict__ out)         // [B,C]
{
    const int c    = blockIdx.x & (C_ - 1);
    const int bt   = blockIdx.x >> 6;      // 0..7
    const int b0   = bt * BT;
    const int tid  = threadIdx.x;
    const int wid  = tid >> 6;             // wave 0..3
    const int lane = tid & 63;
    const int l16  = lane & 15;
    const int lg   = lane >> 4;            // 0..3
    const bool lg0 = (lg == 0);

    __shared__ __align__(16) bf16_t h_lds[2 * HSZ];  // ping-pong h state (bf16)
    __shared__ float x_lds[BT * XS];                 // staged inputs, padded stride

    for (int i = tid; i < 2 * HSZ; i += 256) h_lds[i] = (bf16_t)0.0f;
    for (int i = tid; i < BT * T_; i += 256) {
        const int bl = i >> 8, t = i & 255;
        x_lds[bl * XS + t] = x[(size_t)(b0 + bl) * (T_ * C_) + (size_t)t * C_ + c];
    }

    // ---- per-wave weight fragments. Wave owns gate-cols n = q*128 + wid*32 + 2*l16 + u
    // (interleaved mapping: lane's two cells (u=0,1) are ADJACENT columns -> packed writes)
    bf16x8 bw[4][2][4];      // [gate][u][k-frag]
    bf16x8 b4[4][2];         // augmented K-slot: x*w_ih via (xh*wh + xh*wl + xl*wh)
    float  bias2[4][2];      // fp32 bias, folded into accumulator init
    #pragma unroll
    for (int q = 0; q < 4; ++q) {
        #pragma unroll
        for (int u = 0; u < 2; ++u) {
            const int n = q * 128 + wid * 32 + 2 * l16 + u;
            bias2[q][u] = b_ih[c * G_ + n] + b_hh[c * G_ + n];
            const float wv = w_ih[c * G_ + n];
            const bf16_t wh = (bf16_t)wv;
            const bf16_t wl = (bf16_t)(wv - (float)wh);
            bf16x8 f;
            #pragma unroll
            for (int e = 0; e < 8; ++e) f[e] = (bf16_t)0.0f;
            if (lg0) { f[0] = wh; f[1] = wl; f[2] = wh; }
            b4[q][u] = f;
            #pragma unroll
            for (int kk = 0; kk < 4; ++kk) {
                const int k0 = kk * 32 + lg * 8;
                const float4 wa = *(const float4*)&w_hh[((size_t)(c * G_ + n)) * H_ + k0];
                const float4 wb = *(const float4*)&w_hh[((size_t)(c * G_ + n)) * H_ + k0 + 4];
                bf16x8 g;
                g[0] = (bf16_t)wa.x; g[1] = (bf16_t)wa.y; g[2] = (bf16_t)wa.z; g[3] = (bf16_t)wa.w;
                g[4] = (bf16_t)wb.x; g[5] = (bf16_t)wb.y; g[6] = (bf16_t)wb.z; g[7] = (bf16_t)wb.w;
                bw[q][u][kk] = g;
            }
        }
    }

    float cst[2][4];
    #pragma unroll
    for (int u = 0; u < 2; ++u)
        #pragma unroll
        for (int r = 0; r < 4; ++r) cst[u][r] = 0.0f;

    __syncthreads();

    const int a_base = l16 * HS;            // A-frag: row=l16, k=kk*32+lg*8
    const int row_l  = lg * 4;              // C/D rows this lane owns
    const int colp   = wid * 32 + 2 * l16;  // lane's (even) column pair base

    for (int t = 0; t < T_; ++t) {
        const int rd = (t & 1) * HSZ;
        const int wr = ((t + 1) & 1) * HSZ;

        // A fragments of h (same lane->k map as B: permutation-safe)
        bf16x8 a[4];
        #pragma unroll
        for (int kk = 0; kk < 4; ++kk)
            a[kk] = *(const bf16x8*)&h_lds[rd + a_base + kk * 32 + lg * 8];

        // augmented A fragment: x split hi/lo (only k-group lg==0 holds data)
        const float xv = x_lds[l16 * XS + t];
        const uint32_t p0 = cvt_pk_bf16(xv, xv);
        const float xhf = __uint_as_float(p0 << 16);
        const uint32_t p1 = cvt_pk_bf16(xv - xhf, 0.0f);
        AFrag af;
        af.w[0] = lg0 ? p0 : 0u;
        af.w[1] = lg0 ? p1 : 0u;
        af.w[2] = 0u; af.w[3] = 0u;

        float hn2[2][4];
        #pragma unroll
        for (int u = 0; u < 2; ++u) {
            f32x4 accq[4];
            #pragma unroll
            for (int q = 0; q < 4; ++q) {
                const float bb = bias2[q][u];
                f32x4 acc; acc[0] = bb; acc[1] = bb; acc[2] = bb; acc[3] = bb;
                #pragma unroll
                for (int kk = 0; kk < 4; ++kk)
                    acc = __builtin_amdgcn_mfma_f32_16x16x32_bf16(a[kk], bw[q][u][kk], acc, 0, 0, 0);
                acc = __builtin_amdgcn_mfma_f32_16x16x32_bf16(af.v, b4[q][u], acc, 0, 0, 0);
                accq[q] = acc;
            }
            #pragma unroll
            for (int r = 0; r < 4; ++r) {
                const float ig = sigmoid_fast(accq[0][r]) * tanh_fast(accq[2][r]);
                const float cn = sigmoid_fast(accq[1][r]) * cst[u][r] + ig;
                cst[u][r] = cn;
                hn2[u][r] = sigmoid_fast(accq[3][r]) * tanh_fast(cn);
            }
        }
        // packed adjacent-column writes (4 x ds_write_b32, 4B-strided across l16)
        #pragma unroll
        for (int r = 0; r < 4; ++r) {
            bf16x2 hv; hv[0] = (bf16_t)hn2[0][r]; hv[1] = (bf16_t)hn2[1][r];
            *(bf16x2*)&h_lds[wr + (row_l + r) * HS + colp] = hv;
        }
        __syncthreads();
    }

    // ---- epilogue: out[b][c] = dot(h_T[b,:], w_fc[c,:]) + b_fc[c]; h_T in buffer 0
    #pragma unroll
    for (int rr = 0; rr < 4; ++rr) {
        const int row = wid * 4 + rr;
        const float h0 = (float)h_lds[row * HS + 2 * lane];
        const float h1 = (float)h_lds[row * HS + 2 * lane + 1];
        const float2 wf = *(const float2*)&w_fc[c * H_ + 2 * lane];
        float p = h0 * wf.x + h1 * wf.y;
        #pragma unroll
        for (int off = 32; off; off >>= 1) p += __shfl_xor(p, off);
        if (lane == 0) out[(size_t)(b0 + row) * C_ + c] = p + b_fc[c];
    }
}

extern "C" void kernel_launch(void* const* d_in, const int* in_sizes, int n_in,
                              void* d_out, int out_size, void* d_ws, size_t ws_size,
                              hipStream_t stream) {
    const float* x    = (const float*)d_in[0];
    const float* w_ih = (const float*)d_in[1];
    const float* w_hh = (const float*)d_in[2];
    const float* b_ih = (const float*)d_in[3];
    const float* b_hh = (const float*)d_in[4];
    const float* w_fc = (const float*)d_in[5];
    const float* b_fc = (const float*)d_in[6];
    float* out = (float*)d_out;

    dim3 grid(C_ * (B_ / BT));   // 512 workgroups
    dim3 block(256);
    lstm_fused<<<grid, block, 0, stream>>>(x, w_ih, w_hh, b_ih, b_hh, w_fc, b_fc, out);
}

// Round 3
// 387.608 us; speedup vs baseline: 1.0667x; 1.0261x over previous
//
#include <hip/hip_runtime.h>
#include <hip/hip_bf16.h>

typedef __bf16 bf16_t;
typedef bf16_t bf16x8 __attribute__((ext_vector_type(8)));
typedef float f32x4 __attribute__((ext_vector_type(4)));

#define B_   128
#define T_   256
#define C_   64
#define H_   128
#define G_   512   // 4*H
#define BT   16    // batch rows per workgroup
#define XS   20    // x_lds stride per timestep (floats): 80B, 16B-aligned
#define HBUF 2048  // bf16 elems per h buffer: 16 kgrp * 16 rows * 8

#define K1 1.4426950408889634f   // log2(e)
#define K2 2.8853900817779268f   // 2*log2(e)

__global__ __launch_bounds__(512, 4) void lstm_fused(
    const float* __restrict__ x,     // [B,T,C]
    const float* __restrict__ w_ih,  // [C,4H]
    const float* __restrict__ w_hh,  // [C,4H,H]
    const float* __restrict__ b_ih,  // [C,4H]
    const float* __restrict__ b_hh,  // [C,4H]
    const float* __restrict__ w_fc,  // [C,H]
    const float* __restrict__ b_fc,  // [C]
    float* __restrict__ out)         // [B,C]
{
    const int c    = blockIdx.x & (C_ - 1);
    const int bt   = blockIdx.x >> 6;      // 0..7
    const int b0   = bt * BT;
    const int tid  = threadIdx.x;
    const int w    = tid >> 6;             // wave 0..7
    const int lane = tid & 63;
    const int l16  = lane & 15;
    const int lg   = lane >> 4;            // 0..3

    // h layout: [buf][kgrp(16)][row(16)][e(8)] bf16 -> A-frag reads contiguous
    __shared__ __align__(16) bf16_t h_lds[2 * HBUF];
    // x layout: [t][row] padded to XS floats -> one b128 broadcast per lg
    __shared__ __align__(16) float x_lds[T_ * XS];

    for (int i = tid; i < HBUF; i += 512) ((uint32_t*)h_lds)[i] = 0u;  // 2*HBUF bf16 = HBUF dwords
    for (int i = tid; i < BT * T_; i += 512) {
        const int bl = i >> 8, t = i & 255;
        x_lds[t * XS + bl] = x[(size_t)(b0 + bl) * (T_ * C_) + (size_t)t * C_ + c];
    }

    // ---- weights: wave w owns gate-cols n(q) = q*128 + w*16 + l16 (one col per gate)
    bf16x8 bw[4][4];          // [gate][k-frag] : 64 VGPRs
    float  bias[4], wih[4];
    #pragma unroll
    for (int q = 0; q < 4; ++q) {
        const int n = q * 128 + w * 16 + l16;
        bias[q] = b_ih[c * G_ + n] + b_hh[c * G_ + n];
        wih[q]  = w_ih[c * G_ + n];
        #pragma unroll
        for (int kk = 0; kk < 4; ++kk) {
            const int k0 = kk * 32 + lg * 8;
            const float4 wa = *(const float4*)&w_hh[((size_t)(c * G_ + n)) * H_ + k0];
            const float4 wb = *(const float4*)&w_hh[((size_t)(c * G_ + n)) * H_ + k0 + 4];
            bf16x8 g;
            g[0] = (bf16_t)wa.x; g[1] = (bf16_t)wa.y; g[2] = (bf16_t)wa.z; g[3] = (bf16_t)wa.w;
            g[4] = (bf16_t)wb.x; g[5] = (bf16_t)wb.y; g[6] = (bf16_t)wb.z; g[7] = (bf16_t)wb.w;
            bw[q][kk] = g;
        }
    }

    float cst[4] = {0.f, 0.f, 0.f, 0.f};

    __syncthreads();

    const int a_off  = l16 * 8;                                    // A-frag: row=l16
    const int wbase  = (w * 2 + (l16 >> 3)) * 128 + lg * 32 + (l16 & 7);  // h-write base

    auto step = [&](const int RD, const int WR, const int t) {
        const f32x4 xv = *(const f32x4*)&x_lds[t * XS + lg * 4];   // rows lg*4..+3, broadcast

        bf16x8 a[4];
        #pragma unroll
        for (int kk = 0; kk < 4; ++kk)
            a[kk] = *(const bf16x8*)&h_lds[RD + (kk * 4 + lg) * 128 + a_off];

        f32x4 acc[4];
        #pragma unroll
        for (int q = 0; q < 4; ++q)
            #pragma unroll
            for (int r = 0; r < 4; ++r)
                acc[q][r] = fmaf(xv[r], wih[q], bias[q]);          // x*w_ih + bias as C-init

        #pragma unroll
        for (int q = 0; q < 4; ++q)
            #pragma unroll
            for (int kk = 0; kk < 4; ++kk)
                acc[q] = __builtin_amdgcn_mfma_f32_16x16x32_bf16(a[kk], bw[q][kk], acc[q], 0, 0, 0);

        // activations: shared-rcp form, 5 exp2 + 2 rcp per cell
        #pragma unroll
        for (int r = 0; r < 4; ++r) {
            const float ei = __builtin_amdgcn_exp2f(-K1 * acc[0][r]);
            const float ef = __builtin_amdgcn_exp2f(-K1 * acc[1][r]);
            const float eg = __builtin_amdgcn_exp2f( K2 * acc[2][r]);
            const float eo = __builtin_amdgcn_exp2f(-K1 * acc[3][r]);
            const float A  = 1.f + ei, D = 1.f + ef, Bb = 1.f + eg, O = 1.f + eo;
            const float AB = A * Bb;
            const float r1 = __builtin_amdgcn_rcpf(D * AB);
            const float cn = fmaf(D, eg - 1.f, cst[r] * AB) * r1;  // sig(f)*c + sig(i)*tanh(g)
            cst[r] = cn;
            float m2 = K2 * cn;
            m2 = fminf(fmaxf(m2, -60.f), 60.f);
            const float ec = __builtin_amdgcn_exp2f(m2);
            const float r2 = __builtin_amdgcn_rcpf(O * (1.f + ec));
            const float hv = (ec - 1.f) * r2;                      // sig(o)*tanh(cn)
            h_lds[WR + wbase + r * 8] = (bf16_t)hv;
        }
        __syncthreads();
    };

    for (int t = 0; t < T_; t += 2) {
        step(0, HBUF, t);        // read buf0, write buf1
        step(HBUF, 0, t + 1);    // read buf1, write buf0
    }

    // ---- epilogue: out[b][c] = dot(h_T[b,:], w_fc[c,:]) + b_fc[c]; h_T in buf0
    #pragma unroll
    for (int rr = 0; rr < 2; ++rr) {
        const int row = w * 2 + rr;
        // lane covers k = 2*lane, 2*lane+1 (same kgrp, contiguous)
        const int eaddr = (lane >> 2) * 128 + row * 8 + (lane & 3) * 2;
        const float h0 = (float)h_lds[eaddr];
        const float h1 = (float)h_lds[eaddr + 1];
        const float2 wf = *(const float2*)&w_fc[c * H_ + 2 * lane];
        float p = h0 * wf.x + h1 * wf.y;
        #pragma unroll
        for (int off = 32; off; off >>= 1) p += __shfl_xor(p, off);
        if (lane == 0) out[(size_t)(b0 + row) * C_ + c] = p + b_fc[c];
    }
}

extern "C" void kernel_launch(void* const* d_in, const int* in_sizes, int n_in,
                              void* d_out, int out_size, void* d_ws, size_t ws_size,
                              hipStream_t stream) {
    const float* x    = (const float*)d_in[0];
    const float* w_ih = (const float*)d_in[1];
    const float* w_hh = (const float*)d_in[2];
    const float* b_ih = (const float*)d_in[3];
    const float* b_hh = (const float*)d_in[4];
    const float* w_fc = (const float*)d_in[5];
    const float* b_fc = (const float*)d_in[6];
    float* out = (float*)d_out;

    dim3 grid(C_ * (B_ / BT));   // 512 workgroups
    dim3 block(512);             // 8 waves
    lstm_fused<<<grid, block, 0, stream>>>(x, w_ih, w_hh, b_ih, b_hh, w_fc, b_fc, out);
}

// Round 4
// 347.488 us; speedup vs baseline: 1.1898x; 1.1155x over previous
//
#include <hip/hip_runtime.h>
#include <hip/hip_bf16.h>

typedef __bf16 bf16_t;
typedef bf16_t bf16x8 __attribute__((ext_vector_type(8)));
typedef float f32x4 __attribute__((ext_vector_type(4)));
typedef float f32x2 __attribute__((ext_vector_type(2)));

#define B_   128
#define T_   256
#define C_   64
#define H_   128
#define G_   512   // 4*H
#define BT   16    // batch rows per workgroup
#define HBUF 2048  // bf16 elems per h buffer: 16 kgrp * 16 rows * 8

#define K1 1.4426950408889634f   // log2(e)
#define K2 2.8853900817779268f   // 2*log2(e)

union AF { bf16x8 v; uint32_t w[4]; };

__device__ __forceinline__ uint32_t cvt_pk_bf16(float a, float b) {
    uint32_t r; asm("v_cvt_pk_bf16_f32 %0, %1, %2" : "=v"(r) : "v"(a), "v"(b)); return r;
}
__device__ __forceinline__ f32x2 exp2v(f32x2 z) {
    f32x2 r; r.x = __builtin_amdgcn_exp2f(z.x); r.y = __builtin_amdgcn_exp2f(z.y); return r;
}
__device__ __forceinline__ f32x2 rcpv(f32x2 z) {
    f32x2 r; r.x = __builtin_amdgcn_rcpf(z.x); r.y = __builtin_amdgcn_rcpf(z.y); return r;
}

__global__ __launch_bounds__(512, 4) void lstm_fused(
    const float* __restrict__ x,     // [B,T,C]
    const float* __restrict__ w_ih,  // [C,4H]
    const float* __restrict__ w_hh,  // [C,4H,H]
    const float* __restrict__ b_ih,  // [C,4H]
    const float* __restrict__ b_hh,  // [C,4H]
    const float* __restrict__ w_fc,  // [C,H]
    const float* __restrict__ b_fc,  // [C]
    float* __restrict__ out)         // [B,C]
{
    const int c    = blockIdx.x & (C_ - 1);
    const int bt   = blockIdx.x >> 6;      // 0..7
    const int b0   = bt * BT;
    const int tid  = threadIdx.x;
    const int w    = tid >> 6;             // wave 0..7
    const int lane = tid & 63;
    const int l16  = lane & 15;
    const int lg   = lane >> 4;            // 0..3
    const bool lg0 = (lg == 0);

    // h layout: [buf][kgrp(16)][row(16)][e(8)] bf16 -> conflict-free b128 A reads
    __shared__ __align__(16) bf16_t h_lds[2 * HBUF];   // 8 KB
    __shared__ __align__(16) float x_lds[T_ * BT];     // [t][row], 16 KB

    for (int i = tid; i < HBUF; i += 512) ((uint32_t*)h_lds)[i] = 0u;
    for (int i = tid; i < BT * T_; i += 512) {
        const int bl = i >> 8, t = i & 255;
        x_lds[t * BT + bl] = x[(size_t)(b0 + bl) * (T_ * C_) + (size_t)t * C_ + c];
    }

    // ---- weights (pre-scaled into exp2 domain): wave w owns cols n(q)=q*128+w*16+l16
    // i,f,o scaled by -log2(e); g scaled by +2*log2(e)
    bf16x8 bw[4][4];          // [gate][k-frag] -> AGPR-resident (MFMA-only)
    AF     augb[4];           // augmented K: (wih_h, wih_l, wih_h, bias_h, bias_l, 0,0,0)
    #pragma unroll
    for (int q = 0; q < 4; ++q) {
        const float s = (q == 2) ? K2 : -K1;
        const int n = q * 128 + w * 16 + l16;
        #pragma unroll
        for (int kk = 0; kk < 4; ++kk) {
            const int k0 = kk * 32 + lg * 8;
            const float4 wa = *(const float4*)&w_hh[((size_t)(c * G_ + n)) * H_ + k0];
            const float4 wb = *(const float4*)&w_hh[((size_t)(c * G_ + n)) * H_ + k0 + 4];
            bf16x8 g;
            g[0] = (bf16_t)(s * wa.x); g[1] = (bf16_t)(s * wa.y);
            g[2] = (bf16_t)(s * wa.z); g[3] = (bf16_t)(s * wa.w);
            g[4] = (bf16_t)(s * wb.x); g[5] = (bf16_t)(s * wb.y);
            g[6] = (bf16_t)(s * wb.z); g[7] = (bf16_t)(s * wb.w);
            bw[q][kk] = g;
        }
        const float wv = s * w_ih[c * G_ + n];
        const bf16_t wh = (bf16_t)wv;
        const bf16_t wl = (bf16_t)(wv - (float)wh);
        const float bb = s * (b_ih[c * G_ + n] + b_hh[c * G_ + n]);
        const bf16_t bh = (bf16_t)bb;
        const bf16_t bl2 = (bf16_t)(bb - (float)bh);
        bf16x8 f;
        #pragma unroll
        for (int e = 0; e < 8; ++e) f[e] = (bf16_t)0.0f;
        if (lg0) { f[0] = wh; f[1] = wl; f[2] = wh; f[3] = bh; f[4] = bl2; }
        augb[q].v = f;
    }

    float cst[4] = {0.f, 0.f, 0.f, 0.f};
    const f32x4 zc = {0.f, 0.f, 0.f, 0.f};      // shared zero C-init
    const f32x2 one2 = {1.f, 1.f};

    __syncthreads();

    const int a_off = l16 * 8;                                          // A row = l16
    const int wbase = (w * 2 + (l16 >> 3)) * 128 + lg * 32 + (l16 & 7); // h-write base

    auto step = [&](const int RD, const int WR, const int t) {
        // augmented A: x hi/lo + bias-activators (lg0 lanes only)
        const float xr = x_lds[t * BT + l16];           // broadcast across lg
        const uint32_t p0 = cvt_pk_bf16(xr, xr);        // (xh, xh)
        const float xhf = __uint_as_float(p0 << 16);
        const uint32_t p1 = cvt_pk_bf16(xr - xhf, 1.0f); // (xl, 1.0)
        AF a4;
        a4.w[0] = lg0 ? p0 : 0u;
        a4.w[1] = lg0 ? p1 : 0u;
        a4.w[2] = lg0 ? 0x00003F80u : 0u;                // (1.0bf16, 0)
        a4.w[3] = 0u;

        f32x4 acc[4];
        {   // aug first: x*w_ih + bias from k-slots, zero C-init (shared regs)
            #pragma unroll
            for (int q = 0; q < 4; ++q)
                acc[q] = __builtin_amdgcn_mfma_f32_16x16x32_bf16(a4.v, augb[q].v, zc, 0, 0, 0);
        }
        #pragma unroll
        for (int kk = 0; kk < 4; ++kk) {
            const bf16x8 a = *(const bf16x8*)&h_lds[RD + (kk * 4 + lg) * 128 + a_off];
            #pragma unroll
            for (int q = 0; q < 4; ++q)
                acc[q] = __builtin_amdgcn_mfma_f32_16x16x32_bf16(a, bw[q][kk], acc[q], 0, 0, 0);
        }

        // activations, f32x2 pairs (rows 2p, 2p+1); gates already in exp2 domain
        #pragma unroll
        for (int p = 0; p < 2; ++p) {
            f32x2 zi = {acc[0][2*p], acc[0][2*p+1]};
            f32x2 zf = {acc[1][2*p], acc[1][2*p+1]};
            f32x2 zg = {acc[2][2*p], acc[2][2*p+1]};
            f32x2 zo = {acc[3][2*p], acc[3][2*p+1]};
            const f32x2 ei = exp2v(zi), ef = exp2v(zf), eg = exp2v(zg), eo = exp2v(zo);
            const f32x2 A2 = one2 + ei, D2 = one2 + ef, B2 = one2 + eg, O2 = one2 + eo;
            const f32x2 AB = A2 * B2;
            const f32x2 r1 = rcpv(D2 * AB);
            f32x2 cs = {cst[2*p], cst[2*p+1]};
            const f32x2 cn = (D2 * (eg - one2) + cs * AB) * r1;
            cst[2*p] = cn.x; cst[2*p+1] = cn.y;
            f32x2 m2 = K2 * cn;
            m2 = __builtin_elementwise_min(__builtin_elementwise_max(m2, f32x2{-60.f,-60.f}), f32x2{60.f,60.f});
            const f32x2 ec = exp2v(m2);
            const f32x2 r2 = rcpv(O2 * (one2 + ec));
            const f32x2 hv = (ec - one2) * r2;
            h_lds[WR + wbase + (2*p)   * 8] = (bf16_t)hv.x;
            h_lds[WR + wbase + (2*p+1) * 8] = (bf16_t)hv.y;
        }
        __syncthreads();
    };

    for (int t = 0; t < T_; t += 2) {
        step(0, HBUF, t);        // read buf0, write buf1
        step(HBUF, 0, t + 1);    // read buf1, write buf0
    }

    // ---- epilogue: out[b][c] = dot(h_T[b,:], w_fc[c,:]) + b_fc[c]; h_T in buf0
    #pragma unroll
    for (int rr = 0; rr < 2; ++rr) {
        const int row = w * 2 + rr;
        const int eaddr = (lane >> 2) * 128 + row * 8 + (lane & 3) * 2;  // units 2*lane, 2*lane+1
        const float h0 = (float)h_lds[eaddr];
        const float h1 = (float)h_lds[eaddr + 1];
        const float2 wf = *(const float2*)&w_fc[c * H_ + 2 * lane];
        float p = h0 * wf.x + h1 * wf.y;
        #pragma unroll
        for (int off = 32; off; off >>= 1) p += __shfl_xor(p, off);
        if (lane == 0) out[(size_t)(b0 + row) * C_ + c] = p + b_fc[c];
    }
}

extern "C" void kernel_launch(void* const* d_in, const int* in_sizes, int n_in,
                              void* d_out, int out_size, void* d_ws, size_t ws_size,
                              hipStream_t stream) {
    const float* x    = (const float*)d_in[0];
    const float* w_ih = (const float*)d_in[1];
    const float* w_hh = (const float*)d_in[2];
    const float* b_ih = (const float*)d_in[3];
    const float* b_hh = (const float*)d_in[4];
    const float* w_fc = (const float*)d_in[5];
    const float* b_fc = (const float*)d_in[6];
    float* out = (float*)d_out;

    dim3 grid(C_ * (B_ / BT));   // 512 workgroups
    dim3 block(512);             // 8 waves
    lstm_fused<<<grid, block, 0, stream>>>(x, w_ih, w_hh, b_ih, b_hh, w_fc, b_fc, out);
}